// Round 4
// baseline (562.124 us; speedup 1.0000x reference)
//
#include <hip/hip_runtime.h>
#include <math.h>

#define B_ 16
#define C_ 3
#define H_ 512
#define W_ 512
#define HW_ (H_*W_)              // 262144
#define NFULL (B_*C_*HW_)        // 12582912
#define NHALF (B_*HW_)           // 4194304
#define OUTW 506                 // 512-7+1
#define SROWS 8                  // elem rows per wave-strip
#define NSTRIP 64                // 64*8 = 512 rows
#define NBLK ((48*NSTRIP)/4)     // 768 blocks x 4 waves = 3072 waves

#define INV49 (1.0f/49.0f)
#define COVN  (49.0f/48.0f)
#define C1f   (1e-4f)
#define C2f   (9e-4f)

__device__ __forceinline__ float wred(float v){
  v += __shfl_down(v,32); v += __shfl_down(v,16); v += __shfl_down(v,8);
  v += __shfl_down(v,4);  v += __shfl_down(v,2);  v += __shfl_down(v,1);
  return v;
}

__device__ __forceinline__ float4 mul4(const float4 a,const float4 b){
  float4 r; r.x=a.x*b.x; r.y=a.y*b.y; r.z=a.z*b.z; r.w=a.w*b.w; return r;
}
__device__ __forceinline__ void add8(float4&q0,float4&q1,const float4 n0,const float4 n1){
  q0.x+=n0.x; q0.y+=n0.y; q0.z+=n0.z; q0.w+=n0.w;
  q1.x+=n1.x; q1.y+=n1.y; q1.z+=n1.z; q1.w+=n1.w;
}
__device__ __forceinline__ void upd8(float4&q0,float4&q1,const float4 n0,const float4 n1,
                                     const float4 o0,const float4 o1){
  q0.x+=n0.x-o0.x; q0.y+=n0.y-o0.y; q0.z+=n0.z-o0.z; q0.w+=n0.w-o0.w;
  q1.x+=n1.x-o1.x; q1.y+=n1.y-o1.y; q1.z+=n1.z-o1.z; q1.w+=n1.w-o1.w;
}
__device__ __forceinline__ float a8(const float4 a0,const float4 a1,const float4 b0,const float4 b1){
  return fabsf(a0.x-b0.x)+fabsf(a0.y-b0.y)+fabsf(a0.z-b0.z)+fabsf(a0.w-b0.w)
       + fabsf(a1.x-b1.x)+fabsf(a1.y-b1.y)+fabsf(a1.z-b1.z)+fabsf(a1.w-b1.w);
}
__device__ __forceinline__ float a8m(const float4 a0,const float4 a1,
                                     const float4 m0,const float4 n0,
                                     const float4 m1,const float4 n1){
  return fabsf(a0.x-m0.x*n0.x)+fabsf(a0.y-m0.y*n0.y)+fabsf(a0.z-m0.z*n0.z)+fabsf(a0.w-m0.w*n0.w)
       + fabsf(a1.x-m1.x*n1.x)+fabsf(a1.y-m1.y*n1.y)+fabsf(a1.z-m1.z*n1.z)+fabsf(a1.w-m1.w*n1.w);
}
__device__ __forceinline__ float sq8(const float4 a0,const float4 a1,const float4 b0,const float4 b1){
  float dx=a0.x-b0.x, dy=a0.y-b0.y, dz=a0.z-b0.z, dw=a0.w-b0.w;
  float ex=a1.x-b1.x, ey=a1.y-b1.y, ez=a1.z-b1.z, ew=a1.w-b1.w;
  return dx*dx+dy*dy+dz*dz+dw*dw + ex*ex+ey*ey+ez*ez+ew*ew;
}

// horizontal 7-window sums: lane holds v[0..7] (cols 8L..8L+7); needs next
// lane's v[0..5]. Produces 8 window sums. No barrier - pure cross-lane.
__device__ __forceinline__ void hwin(const float4 v0,const float4 v1,float* o){
  float n0=__shfl_down(v0.x,1), n1=__shfl_down(v0.y,1), n2=__shfl_down(v0.z,1);
  float n3=__shfl_down(v0.w,1), n4=__shfl_down(v1.x,1), n5=__shfl_down(v1.y,1);
  float s=v0.x+v0.y+v0.z+v0.w+v1.x+v1.y+v1.z;
  o[0]=s; s+=v1.w-v0.x; o[1]=s; s+=n0-v0.y; o[2]=s; s+=n1-v0.z; o[3]=s;
  s+=n2-v0.w; o[4]=s; s+=n3-v1.x; o[5]=s; s+=n4-v1.y; o[6]=s; s+=n5-v1.z; o[7]=s;
}

__device__ __forceinline__ float ssim8(
    const float4 X0,const float4 X1,const float4 Y0,const float4 Y1,
    const float4 XX0,const float4 XX1,const float4 YY0,const float4 YY1,
    const float4 XY0,const float4 XY1,const int lim){
  float hx[8],hy[8],hxx[8],hyy[8],hxy[8];
  hwin(X0,X1,hx); hwin(Y0,Y1,hy); hwin(XX0,XX1,hxx); hwin(YY0,YY1,hyy); hwin(XY0,XY1,hxy);
  float acc=0.f;
  #pragma unroll
  for(int k=0;k<8;k++){
    if(k<lim){
      float ux=hx[k]*INV49, uy=hy[k]*INV49;
      float uxuy=ux*uy;
      float vx=COVN*(hxx[k]*INV49-ux*ux);
      float vy=COVN*(hyy[k]*INV49-uy*uy);
      float vxy=COVN*(hxy[k]*INV49-uxuy);
      float num=(2.f*uxuy+C1f)*(2.f*vxy+C2f);
      float den=(ux*ux+uy*uy+C1f)*(vx+vy+C2f);
      acc += num/den;
    }
  }
  return acc;
}

// One wave = one (bc, 8-row strip). Both SSIM pairs + all elementwise terms +
// target histogram. NO __syncthreads in the hot loop.
__global__ __launch_bounds__(256,3) void k_mega(
    const float* __restrict__ img, const float* __restrict__ tgt,
    const float* __restrict__ c0,  const float* __restrict__ c1,
    const float* __restrict__ c2,  const float* __restrict__ r0,
    const float* __restrict__ r1,
    double* __restrict__ acc, unsigned int* __restrict__ bins){
  __shared__ unsigned int hist[4][256];
  __shared__ float sred[4][8];
  const int t = threadIdx.x;
  const int w = t>>6, L = t&63;
  const int wid = blockIdx.x*4 + w;
  const int bc = wid >> 6;                 // 0..47 (same for all 4 waves of a block)
  const int strip = wid & (NSTRIP-1);      // 0..63
  const int b = bc/3;
  const bool do_c2 = (bc - b*3) == 0;

  const float* xA = c0  + (size_t)bc*HW_;   // comp0
  const float* yA = r0  + (size_t)bc*HW_;   // real_comp0
  const float* xB = img + (size_t)bc*HW_;   // img
  const float* yB = tgt + (size_t)bc*HW_;   // target
  const float* c1b = c1 + (size_t)b*HW_;
  const float* r1b = r1 + (size_t)b*HW_;
  const float* c2b = c2 + (size_t)b*HW_;

  const int i0 = strip*SROWS;
  const int iEnd = min(i0+SROWS, OUTW);
  const int eEnd = i0+SROWS;
  const int c = 8*L;                        // this lane's 8 columns
  const int lim = OUTW - c;                 // valid outputs (>=2)

  hist[w][L]=0u; hist[w][L+64]=0u; hist[w][L+128]=0u; hist[w][L+192]=0u;
  unsigned int* mh = hist[w];               // wave-private: no barrier needed

  auto LD =[&](const float* p,int r)->float4{ return *(const float4*)(p+(size_t)r*W_+c); };
  auto LD2=[&](const float* p,int r)->float4{ return *(const float4*)(p+(size_t)r*W_+c+4); };
  auto hist8=[&](const float4 v0,const float4 v1){
    int h0=min(max(__float2int_rn(v0.x*255.f),0),255);
    int h1=min(max(__float2int_rn(v0.y*255.f),0),255);
    int h2=min(max(__float2int_rn(v0.z*255.f),0),255);
    int h3=min(max(__float2int_rn(v0.w*255.f),0),255);
    int h4=min(max(__float2int_rn(v1.x*255.f),0),255);
    int h5=min(max(__float2int_rn(v1.y*255.f),0),255);
    int h6=min(max(__float2int_rn(v1.z*255.f),0),255);
    int h7=min(max(__float2int_rn(v1.w*255.f),0),255);
    atomicAdd(&mh[h0],1u); atomicAdd(&mh[h1],1u); atomicAdd(&mh[h2],1u); atomicAdd(&mh[h3],1u);
    atomicAdd(&mh[h4],1u); atomicAdd(&mh[h5],1u); atomicAdd(&mh[h6],1u); atomicAdd(&mh[h7],1u);
  };

  float4 z={0.f,0.f,0.f,0.f};
  float4 Ax0=z,Ax1=z,Ay0=z,Ay1=z,Axx0=z,Axx1=z,Ayy0=z,Ayy1=z,Axy0=z,Axy1=z;
  float4 Bx0=z,Bx1=z,By0=z,By1=z,Bxx0=z,Bxx1=z,Byy0=z,Byy1=z,Bxy0=z,Bxy1=z;
  float s0=0.f,s1=0.f,s2=0.f,s3=0.f,s4=0.f,accA=0.f,accB=0.f;

  // ---- init: vertical sums over rows [i0, i0+7); these rows are elem rows ----
  #pragma unroll 1
  for(int r=i0; r<i0+7; ++r){
    float4 xa0=LD(xA,r), xa1=LD2(xA,r), ya0=LD(yA,r), ya1=LD2(yA,r);
    float4 xb0=LD(xB,r), xb1=LD2(xB,r), yb0=LD(yB,r), yb1=LD2(yB,r);
    float4 cv0=LD(c1b,r), cv1=LD2(c1b,r), rv0=LD(r1b,r), rv1=LD2(r1b,r);
    add8(Ax0,Ax1,xa0,xa1); add8(Ay0,Ay1,ya0,ya1);
    add8(Axx0,Axx1,mul4(xa0,xa0),mul4(xa1,xa1));
    add8(Ayy0,Ayy1,mul4(ya0,ya0),mul4(ya1,ya1));
    add8(Axy0,Axy1,mul4(xa0,ya0),mul4(xa1,ya1));
    add8(Bx0,Bx1,xb0,xb1); add8(By0,By1,yb0,yb1);
    add8(Bxx0,Bxx1,mul4(xb0,xb0),mul4(xb1,xb1));
    add8(Byy0,Byy1,mul4(yb0,yb0),mul4(yb1,yb1));
    add8(Bxy0,Bxy1,mul4(xb0,yb0),mul4(xb1,yb1));
    s0 += a8(xa0,xa1,ya0,ya1);
    s1 += a8m(xb0,xb1, xa0,cv0, xa1,cv1);
    s2 += a8m(yb0,yb1, ya0,rv0, ya1,rv1);
    s3 += sq8(xb0,xb1,yb0,yb1);
    if(do_c2){ float4 e0=LD(c2b,r), e1=LD2(c2b,r); s4 += sq8(e0,e1,rv0,rv1); }
    hist8(yb0,yb1);
  }

  // ---- main: barrier-free sliding window over output rows ----
  #pragma unroll 1
  for(int i=i0; i<iEnd; ++i){
    const bool up = (i+1 < iEnd);
    const int  rn = i+7;
    const bool de = up && (rn < eEnd);

    float4 xan0,xan1,yan0,yan1,xao0,xao1,yao0,yao1;
    if(up){
      xan0=LD(xA,rn); xan1=LD2(xA,rn); yan0=LD(yA,rn); yan1=LD2(yA,rn);
      xao0=LD(xA,i);  xao1=LD2(xA,i);  yao0=LD(yA,i);  yao1=LD2(yA,i);
    }
    accA += ssim8(Ax0,Ax1,Ay0,Ay1,Axx0,Axx1,Ayy0,Ayy1,Axy0,Axy1, lim);
    if(up){
      upd8(Ax0,Ax1,xan0,xan1,xao0,xao1);
      upd8(Ay0,Ay1,yan0,yan1,yao0,yao1);
      upd8(Axx0,Axx1,mul4(xan0,xan0),mul4(xan1,xan1),mul4(xao0,xao0),mul4(xao1,xao1));
      upd8(Ayy0,Ayy1,mul4(yan0,yan0),mul4(yan1,yan1),mul4(yao0,yao0),mul4(yao1,yao1));
      upd8(Axy0,Axy1,mul4(xan0,yan0),mul4(xan1,yan1),mul4(xao0,yao0),mul4(xao1,yao1));
    }

    float4 xbn0,xbn1,ybn0,ybn1,xbo0,xbo1,ybo0,ybo1,cv0,cv1,rv0,rv1;
    if(up){
      xbn0=LD(xB,rn); xbn1=LD2(xB,rn); ybn0=LD(yB,rn); ybn1=LD2(yB,rn);
      xbo0=LD(xB,i);  xbo1=LD2(xB,i);  ybo0=LD(yB,i);  ybo1=LD2(yB,i);
    }
    if(de){ cv0=LD(c1b,rn); cv1=LD2(c1b,rn); rv0=LD(r1b,rn); rv1=LD2(r1b,rn); }
    accB += ssim8(Bx0,Bx1,By0,By1,Bxx0,Bxx1,Byy0,Byy1,Bxy0,Bxy1, lim);
    if(up){
      upd8(Bx0,Bx1,xbn0,xbn1,xbo0,xbo1);
      upd8(By0,By1,ybn0,ybn1,ybo0,ybo1);
      upd8(Bxx0,Bxx1,mul4(xbn0,xbn0),mul4(xbn1,xbn1),mul4(xbo0,xbo0),mul4(xbo1,xbo1));
      upd8(Byy0,Byy1,mul4(ybn0,ybn0),mul4(ybn1,ybn1),mul4(ybo0,ybo0),mul4(ybo1,ybo1));
      upd8(Bxy0,Bxy1,mul4(xbn0,ybn0),mul4(xbn1,ybn1),mul4(xbo0,ybo0),mul4(xbo1,ybo1));
    }
    if(de){
      s0 += a8(xan0,xan1,yan0,yan1);
      s1 += a8m(xbn0,xbn1, xan0,cv0, xan1,cv1);
      s2 += a8m(ybn0,ybn1, yan0,rv0, yan1,rv1);
      s3 += sq8(xbn0,xbn1,ybn0,ybn1);
      if(do_c2){ float4 e0=LD(c2b,rn), e1=LD2(c2b,rn); s4 += sq8(e0,e1,rv0,rv1); }
      hist8(ybn0,ybn1);
    }
  }

  // ---- single end-of-block reduction ----
  float v[7]={s0,s1,s2,s3,s4,accA,accB};
  #pragma unroll
  for(int k=0;k<7;k++){ float r=wred(v[k]); if(L==0) sred[w][k]=r; }
  __syncthreads();
  if(t<7){
    double tt=(double)(sred[0][t]+sred[1][t]+sred[2][t]+sred[3][t]);
    int idx=(t<5)? t : t+1;   // acc[0..4], acc[6], acc[7]
    atomicAdd(&acc[idx], tt);
  }
  unsigned int hv = hist[0][t&255]+hist[1][t&255]+hist[2][t&255]+hist[3][t&255];
  atomicAdd(&bins[bc*256+t], hv);   // blockDim==256, all 4 waves share bc
}

// ---------------- final combine ----------------
__global__ __launch_bounds__(256) void k_final(
    const float* __restrict__ chist, const float* __restrict__ score,
    const double* __restrict__ acc, const unsigned int* __restrict__ bins,
    float* __restrict__ out){
  const int tid = threadIdx.x;
  float cpart = 0.f;
  for(int i=tid; i<B_*C_*256; i+=256){
    float h = (float)bins[i] * (1.0f/(float)HW_);
    cpart += fabsf(chist[i]-h);
  }
  float gpart = 0.f;
  if(tid < B_){
    float x = -score[tid];
    gpart = (x > 0.f) ? (x + log1pf(expf(-x))) : log1pf(expf(x));
  }
  __shared__ float sc[4], sg[4];
  float rc=wred(cpart), rg=wred(gpart);
  const int wid=tid>>6, lane=tid&63;
  if(lane==0){ sc[wid]=rc; sg[wid]=rg; }
  __syncthreads();
  if(tid==0){
    float colorsum = sc[0]+sc[1]+sc[2]+sc[3];
    float gansum   = sg[0]+sg[1]+sg[2]+sg[3];
    double nfull = (double)NFULL;
    double m0 = acc[0]/nfull, m1 = acc[1]/nfull, m2 = acc[2]/nfull, mse = acc[3]/nfull;
    double light = acc[4]/(double)NHALF;
    double nss = (double)(B_*C_) * (double)OUTW * (double)OUTW;
    double ssimA = acc[6]/nss;
    double ssimB = acc[7]/nss;
    float r_loss   = (float)((1.0-ssimA)+m0+m1+m2);
    float out_loss = (float)((1.0-ssimB)+mse);
    float color    = colorsum * (1.0f/(float)(B_*C_*256));
    float gan      = gansum * (1.0f/(float)B_);
    float lightf   = (float)light;
    float loss = r_loss + lightf + 0.1f*color + out_loss + 0.05f*gan;
    out[0]=loss; out[1]=loss; out[2]=r_loss; out[3]=lightf;
    out[4]=color; out[5]=out_loss; out[6]=gan;
  }
}

extern "C" void kernel_launch(void* const* d_in, const int* in_sizes, int n_in,
                              void* d_out, int out_size, void* d_ws, size_t ws_size,
                              hipStream_t stream) {
  const float* img    = (const float*)d_in[0];
  const float* target = (const float*)d_in[1];
  const float* comp0  = (const float*)d_in[2];
  const float* comp1  = (const float*)d_in[3];
  const float* comp2  = (const float*)d_in[4];
  const float* rc0    = (const float*)d_in[5];
  const float* rc1    = (const float*)d_in[6];
  const float* chist  = (const float*)d_in[7];
  const float* score  = (const float*)d_in[8];

  double* acc = (double*)d_ws;                                   // 8 doubles
  unsigned int* bins = (unsigned int*)((char*)d_ws + 128);       // 48*256 uints

  hipMemsetAsync(d_ws, 0, 128 + (size_t)B_*C_*256*4, stream);

  k_mega<<<NBLK, 256, 0, stream>>>(img, target, comp0, comp1, comp2,
                                   rc0, rc1, acc, bins);
  k_final<<<1, 256, 0, stream>>>(chist, score, acc, bins, (float*)d_out);
}

// Round 5
// 303.704 us; speedup vs baseline: 1.8509x; 1.8509x over previous
//
#include <hip/hip_runtime.h>
#include <math.h>

#define B_ 16
#define C_ 3
#define H_ 512
#define W_ 512
#define HW_ (H_*W_)              // 262144
#define NFULL (B_*C_*HW_)        // 12582912
#define NHALF (B_*HW_)           // 4194304
#define OUTW 506                 // 512-7+1
#define SROWS 16                 // rows per wave-strip
#define NSTRIP 32                // 32*16 = 512 rows
#define NGRP 8                   // 8 groups x 4 waves = 32 strips
#define NBLK_HALF (48*NGRP)      // 384 blocks per pair
#define NBLK (2*NBLK_HALF)       // 768 blocks total = 3 blocks/CU

#define INV49 (1.0f/49.0f)
#define COVN  (49.0f/48.0f)
#define C1f   (1e-4f)
#define C2f   (9e-4f)

__device__ __forceinline__ float wred(float v){
  v += __shfl_down(v,32); v += __shfl_down(v,16); v += __shfl_down(v,8);
  v += __shfl_down(v,4);  v += __shfl_down(v,2);  v += __shfl_down(v,1);
  return v;
}
__device__ __forceinline__ float4 mul4(const float4 a,const float4 b){
  float4 r; r.x=a.x*b.x; r.y=a.y*b.y; r.z=a.z*b.z; r.w=a.w*b.w; return r;
}
__device__ __forceinline__ void add8(float4&q0,float4&q1,const float4 n0,const float4 n1){
  q0.x+=n0.x; q0.y+=n0.y; q0.z+=n0.z; q0.w+=n0.w;
  q1.x+=n1.x; q1.y+=n1.y; q1.z+=n1.z; q1.w+=n1.w;
}
__device__ __forceinline__ void upd8(float4&q0,float4&q1,const float4 n0,const float4 n1,
                                     const float4 o0,const float4 o1){
  q0.x+=n0.x-o0.x; q0.y+=n0.y-o0.y; q0.z+=n0.z-o0.z; q0.w+=n0.w-o0.w;
  q1.x+=n1.x-o1.x; q1.y+=n1.y-o1.y; q1.z+=n1.z-o1.z; q1.w+=n1.w-o1.w;
}
__device__ __forceinline__ float a8(const float4 a0,const float4 a1,const float4 b0,const float4 b1){
  return fabsf(a0.x-b0.x)+fabsf(a0.y-b0.y)+fabsf(a0.z-b0.z)+fabsf(a0.w-b0.w)
       + fabsf(a1.x-b1.x)+fabsf(a1.y-b1.y)+fabsf(a1.z-b1.z)+fabsf(a1.w-b1.w);
}
__device__ __forceinline__ float a8m(const float4 a0,const float4 a1,
                                     const float4 m0,const float4 n0,
                                     const float4 m1,const float4 n1){
  return fabsf(a0.x-m0.x*n0.x)+fabsf(a0.y-m0.y*n0.y)+fabsf(a0.z-m0.z*n0.z)+fabsf(a0.w-m0.w*n0.w)
       + fabsf(a1.x-m1.x*n1.x)+fabsf(a1.y-m1.y*n1.y)+fabsf(a1.z-m1.z*n1.z)+fabsf(a1.w-m1.w*n1.w);
}
__device__ __forceinline__ float sq8(const float4 a0,const float4 a1,const float4 b0,const float4 b1){
  float dx=a0.x-b0.x, dy=a0.y-b0.y, dz=a0.z-b0.z, dw=a0.w-b0.w;
  float ex=a1.x-b1.x, ey=a1.y-b1.y, ez=a1.z-b1.z, ew=a1.w-b1.w;
  return dx*dx+dy*dy+dz*dz+dw*dw + ex*ex+ey*ey+ez*ez+ew*ew;
}

// horizontal 7-window running sums across 8 cols/lane, halo via shfl (no barrier)
__device__ __forceinline__ void hwin(const float4 v0,const float4 v1,float* o){
  float n0=__shfl_down(v0.x,1), n1=__shfl_down(v0.y,1), n2=__shfl_down(v0.z,1);
  float n3=__shfl_down(v0.w,1), n4=__shfl_down(v1.x,1), n5=__shfl_down(v1.y,1);
  float s=v0.x+v0.y+v0.z+v0.w+v1.x+v1.y+v1.z;
  o[0]=s; s+=v1.w-v0.x; o[1]=s; s+=n0-v0.y; o[2]=s; s+=n1-v0.z; o[3]=s;
  s+=n2-v0.w; o[4]=s; s+=n3-v1.x; o[5]=s; s+=n4-v1.y; o[6]=s; s+=n5-v1.z; o[7]=s;
}

__device__ __forceinline__ float ssim8(
    const float4 X0,const float4 X1,const float4 Y0,const float4 Y1,
    const float4 XX0,const float4 XX1,const float4 YY0,const float4 YY1,
    const float4 XY0,const float4 XY1,const int lim){
  float hx[8],hy[8],hxx[8],hyy[8],hxy[8];
  hwin(X0,X1,hx); hwin(Y0,Y1,hy); hwin(XX0,XX1,hxx); hwin(YY0,YY1,hyy); hwin(XY0,XY1,hxy);
  float acc=0.f;
  #pragma unroll
  for(int k=0;k<8;k++){
    if(k<lim){
      float ux=hx[k]*INV49, uy=hy[k]*INV49;
      float uxuy=ux*uy;
      float vx=COVN*(hxx[k]*INV49-ux*ux);
      float vy=COVN*(hyy[k]*INV49-uy*uy);
      float vxy=COVN*(hxy[k]*INV49-uxuy);
      float num=(2.f*uxuy+C1f)*(2.f*vxy+C2f);
      float den=(ux*ux+uy*uy+C1f)*(vx+vy+C2f);
      acc += num*__builtin_amdgcn_rcpf(den);
    }
  }
  return acc;
}

// One wave = ONE SSIM pair on one 16-row strip. No __syncthreads in hot loop.
// A-blocks (bid<384): pair comp0/rc0 -> ssimA, s0=|c0-r0|, s1=|img-c0*c1|
// B-blocks: pair img/tgt -> ssimB, s3=(img-tgt)^2, s2=|tgt-r0*r1|, s4, hist(tgt)
__global__ __launch_bounds__(256,3) void k_mega(
    const float* __restrict__ img, const float* __restrict__ tgt,
    const float* __restrict__ c0,  const float* __restrict__ c1,
    const float* __restrict__ c2,  const float* __restrict__ r0,
    const float* __restrict__ r1,
    double* __restrict__ acc, unsigned int* __restrict__ bins){
  __shared__ unsigned int hist[4][256];
  __shared__ float sred[4][4];
  const int t = threadIdx.x, w = t>>6, L = t&63;
  const int bid = blockIdx.x;
  const bool isA = bid < NBLK_HALF;
  const int hb = isA ? bid : bid - NBLK_HALF;
  const int bc = hb >> 3;                  // 0..47
  const int g  = hb & 7;
  const int strip = g*4 + w;               // 0..31
  const int b = bc/3;
  const bool do_c2 = (bc - b*3) == 0;
  const int i0 = strip*SROWS;
  const int iEnd = min(i0+SROWS, OUTW);
  const int eEnd = i0+SROWS;
  const int c = 8*L;
  const int lim = OUTW - c;                // >= 2

  auto LD =[&](const float* p,int r)->float4{ return *(const float4*)(p+(size_t)r*W_+c); };
  auto LD2=[&](const float* p,int r)->float4{ return *(const float4*)(p+(size_t)r*W_+c+4); };

  float4 z={0.f,0.f,0.f,0.f};
  float4 X0=z,X1=z,Y0=z,Y1=z,XX0=z,XX1=z,YY0=z,YY1=z,XY0=z,XY1=z;

  if(isA){
    const float* X = c0 + (size_t)bc*HW_;
    const float* Y = r0 + (size_t)bc*HW_;
    const float* I = img + (size_t)bc*HW_;
    const float* Cv = c1 + (size_t)b*HW_;
    float s0=0.f, s1=0.f, accS=0.f;

    #pragma unroll 1
    for(int r=i0; r<i0+7; ++r){
      float4 xa0=LD(X,r), xa1=LD2(X,r), ya0=LD(Y,r), ya1=LD2(Y,r);
      float4 iv0=LD(I,r), iv1=LD2(I,r), cv0=LD(Cv,r), cv1=LD2(Cv,r);
      add8(X0,X1,xa0,xa1); add8(Y0,Y1,ya0,ya1);
      add8(XX0,XX1,mul4(xa0,xa0),mul4(xa1,xa1));
      add8(YY0,YY1,mul4(ya0,ya0),mul4(ya1,ya1));
      add8(XY0,XY1,mul4(xa0,ya0),mul4(xa1,ya1));
      s0 += a8(xa0,xa1,ya0,ya1);
      s1 += a8m(iv0,iv1, xa0,cv0, xa1,cv1);
    }
    #pragma unroll 1
    for(int i=i0; i<iEnd; ++i){
      const bool up = (i+1 < iEnd);
      const int  rn = i+7;
      const bool de = up && (rn < eEnd);
      float4 xn0,xn1,yn0,yn1,xo0,xo1,yo0,yo1,iv0,iv1,cv0,cv1;
      if(up){
        xn0=LD(X,rn); xn1=LD2(X,rn); yn0=LD(Y,rn); yn1=LD2(Y,rn);
        xo0=LD(X,i);  xo1=LD2(X,i);  yo0=LD(Y,i);  yo1=LD2(Y,i);
      }
      if(de){ iv0=LD(I,rn); iv1=LD2(I,rn); cv0=LD(Cv,rn); cv1=LD2(Cv,rn); }
      accS += ssim8(X0,X1,Y0,Y1,XX0,XX1,YY0,YY1,XY0,XY1, lim);
      if(up){
        upd8(X0,X1,xn0,xn1,xo0,xo1);
        upd8(Y0,Y1,yn0,yn1,yo0,yo1);
        upd8(XX0,XX1,mul4(xn0,xn0),mul4(xn1,xn1),mul4(xo0,xo0),mul4(xo1,xo1));
        upd8(YY0,YY1,mul4(yn0,yn0),mul4(yn1,yn1),mul4(yo0,yo0),mul4(yo1,yo1));
        upd8(XY0,XY1,mul4(xn0,yn0),mul4(xn1,yn1),mul4(xo0,yo0),mul4(xo1,yo1));
      }
      if(de){
        s0 += a8(xn0,xn1,yn0,yn1);
        s1 += a8m(iv0,iv1, xn0,cv0, xn1,cv1);
      }
    }
    float v[3]={s0,s1,accS};
    #pragma unroll
    for(int k=0;k<3;k++){ float r=wred(v[k]); if(L==0 && k<3) sred[w][k]=r; }
    __syncthreads();
    if(t<3){
      int idx = (t==2)? 6 : t;
      atomicAdd(&acc[idx],(double)(sred[0][t]+sred[1][t]+sred[2][t]+sred[3][t]));
    }
  } else {
    const float* X = img + (size_t)bc*HW_;
    const float* Y = tgt + (size_t)bc*HW_;
    const float* P = r0 + (size_t)bc*HW_;
    const float* Q = r1 + (size_t)b*HW_;
    const float* E = c2 + (size_t)b*HW_;
    float s2=0.f, s3=0.f, s4=0.f, accS=0.f;

    hist[w][L]=0u; hist[w][L+64]=0u; hist[w][L+128]=0u; hist[w][L+192]=0u;
    unsigned int* mh = hist[w];              // wave-private
    auto hist8=[&](const float4 v0,const float4 v1){
      int h0=min(max(__float2int_rn(v0.x*255.f),0),255);
      int h1=min(max(__float2int_rn(v0.y*255.f),0),255);
      int h2=min(max(__float2int_rn(v0.z*255.f),0),255);
      int h3=min(max(__float2int_rn(v0.w*255.f),0),255);
      int h4=min(max(__float2int_rn(v1.x*255.f),0),255);
      int h5=min(max(__float2int_rn(v1.y*255.f),0),255);
      int h6=min(max(__float2int_rn(v1.z*255.f),0),255);
      int h7=min(max(__float2int_rn(v1.w*255.f),0),255);
      atomicAdd(&mh[h0],1u); atomicAdd(&mh[h1],1u); atomicAdd(&mh[h2],1u); atomicAdd(&mh[h3],1u);
      atomicAdd(&mh[h4],1u); atomicAdd(&mh[h5],1u); atomicAdd(&mh[h6],1u); atomicAdd(&mh[h7],1u);
    };

    #pragma unroll 1
    for(int r=i0; r<i0+7; ++r){
      float4 xb0=LD(X,r), xb1=LD2(X,r), yb0=LD(Y,r), yb1=LD2(Y,r);
      float4 p0=LD(P,r), p1=LD2(P,r), q0=LD(Q,r), q1=LD2(Q,r);
      add8(X0,X1,xb0,xb1); add8(Y0,Y1,yb0,yb1);
      add8(XX0,XX1,mul4(xb0,xb0),mul4(xb1,xb1));
      add8(YY0,YY1,mul4(yb0,yb0),mul4(yb1,yb1));
      add8(XY0,XY1,mul4(xb0,yb0),mul4(xb1,yb1));
      s3 += sq8(xb0,xb1,yb0,yb1);
      s2 += a8m(yb0,yb1, p0,q0, p1,q1);
      if(do_c2){ float4 e0=LD(E,r), e1=LD2(E,r); s4 += sq8(e0,e1,q0,q1); }
      hist8(yb0,yb1);
    }
    #pragma unroll 1
    for(int i=i0; i<iEnd; ++i){
      const bool up = (i+1 < iEnd);
      const int  rn = i+7;
      const bool de = up && (rn < eEnd);
      float4 xn0,xn1,yn0,yn1,xo0,xo1,yo0,yo1,p0,p1,q0,q1;
      if(up){
        xn0=LD(X,rn); xn1=LD2(X,rn); yn0=LD(Y,rn); yn1=LD2(Y,rn);
        xo0=LD(X,i);  xo1=LD2(X,i);  yo0=LD(Y,i);  yo1=LD2(Y,i);
      }
      if(de){ p0=LD(P,rn); p1=LD2(P,rn); q0=LD(Q,rn); q1=LD2(Q,rn); }
      accS += ssim8(X0,X1,Y0,Y1,XX0,XX1,YY0,YY1,XY0,XY1, lim);
      if(up){
        upd8(X0,X1,xn0,xn1,xo0,xo1);
        upd8(Y0,Y1,yn0,yn1,yo0,yo1);
        upd8(XX0,XX1,mul4(xn0,xn0),mul4(xn1,xn1),mul4(xo0,xo0),mul4(xo1,xo1));
        upd8(YY0,YY1,mul4(yn0,yn0),mul4(yn1,yn1),mul4(yo0,yo0),mul4(yo1,yo1));
        upd8(XY0,XY1,mul4(xn0,yn0),mul4(xn1,yn1),mul4(xo0,yo0),mul4(xo1,yo1));
      }
      if(de){
        s3 += sq8(xn0,xn1,yn0,yn1);
        s2 += a8m(yn0,yn1, p0,q0, p1,q1);
        if(do_c2){ float4 e0=LD(E,rn), e1=LD2(E,rn); s4 += sq8(e0,e1,q0,q1); }
        hist8(yn0,yn1);
      }
    }
    float v[4]={s2,s3,s4,accS};
    #pragma unroll
    for(int k=0;k<4;k++){ float r=wred(v[k]); if(L==0) sred[w][k]=r; }
    __syncthreads();
    if(t<4){
      int idx = (t==3)? 7 : t+2;
      atomicAdd(&acc[idx],(double)(sred[0][t]+sred[1][t]+sred[2][t]+sred[3][t]));
    }
    unsigned int hv = hist[0][t]+hist[1][t]+hist[2][t]+hist[3][t];
    atomicAdd(&bins[bc*256+t], hv);
  }
}

// ---------------- final combine ----------------
__global__ __launch_bounds__(256) void k_final(
    const float* __restrict__ chist, const float* __restrict__ score,
    const double* __restrict__ acc, const unsigned int* __restrict__ bins,
    float* __restrict__ out){
  const int tid = threadIdx.x;
  float cpart = 0.f;
  for(int i=tid; i<B_*C_*256; i+=256){
    float h = (float)bins[i] * (1.0f/(float)HW_);
    cpart += fabsf(chist[i]-h);
  }
  float gpart = 0.f;
  if(tid < B_){
    float x = -score[tid];
    gpart = (x > 0.f) ? (x + log1pf(expf(-x))) : log1pf(expf(x));
  }
  __shared__ float sc[4], sg[4];
  float rc=wred(cpart), rg=wred(gpart);
  const int wid=tid>>6, lane=tid&63;
  if(lane==0){ sc[wid]=rc; sg[wid]=rg; }
  __syncthreads();
  if(tid==0){
    float colorsum = sc[0]+sc[1]+sc[2]+sc[3];
    float gansum   = sg[0]+sg[1]+sg[2]+sg[3];
    double nfull = (double)NFULL;
    double m0 = acc[0]/nfull, m1 = acc[1]/nfull, m2 = acc[2]/nfull, mse = acc[3]/nfull;
    double light = acc[4]/(double)NHALF;
    double nss = (double)(B_*C_) * (double)OUTW * (double)OUTW;
    double ssimA = acc[6]/nss;
    double ssimB = acc[7]/nss;
    float r_loss   = (float)((1.0-ssimA)+m0+m1+m2);
    float out_loss = (float)((1.0-ssimB)+mse);
    float color    = colorsum * (1.0f/(float)(B_*C_*256));
    float gan      = gansum * (1.0f/(float)B_);
    float lightf   = (float)light;
    float loss = r_loss + lightf + 0.1f*color + out_loss + 0.05f*gan;
    out[0]=loss; out[1]=loss; out[2]=r_loss; out[3]=lightf;
    out[4]=color; out[5]=out_loss; out[6]=gan;
  }
}

extern "C" void kernel_launch(void* const* d_in, const int* in_sizes, int n_in,
                              void* d_out, int out_size, void* d_ws, size_t ws_size,
                              hipStream_t stream) {
  const float* img    = (const float*)d_in[0];
  const float* target = (const float*)d_in[1];
  const float* comp0  = (const float*)d_in[2];
  const float* comp1  = (const float*)d_in[3];
  const float* comp2  = (const float*)d_in[4];
  const float* rc0    = (const float*)d_in[5];
  const float* rc1    = (const float*)d_in[6];
  const float* chist  = (const float*)d_in[7];
  const float* score  = (const float*)d_in[8];

  double* acc = (double*)d_ws;                                   // 8 doubles
  unsigned int* bins = (unsigned int*)((char*)d_ws + 128);       // 48*256 uints

  hipMemsetAsync(d_ws, 0, 128 + (size_t)B_*C_*256*4, stream);

  k_mega<<<NBLK, 256, 0, stream>>>(img, target, comp0, comp1, comp2,
                                   rc0, rc1, acc, bins);
  k_final<<<1, 256, 0, stream>>>(chist, score, acc, bins, (float*)d_out);
}